// Round 7
// baseline (345.947 us; speedup 1.0000x reference)
//
#include <hip/hip_runtime.h>

// SparseDIA (9 static offsets) @ dense: out[r,c] = sum_k diags[k, r+off_k] * other[r+off_k, c]
// N=8192, M=4096, fp32.
//
// R4-R6 post-mortem: occupancy, conflicts, and barrier-vs-counted-vmcnt all varied;
// time pinned at 86-91us -> the residual is block-level COUPLING (per-band barrier
// ties 8-16 waves to the slowest wave's stall). Round-7: wave-autonomous pipeline.
// Each WAVE owns one f4 column x 2048 rows with a PRIVATE 8 KB LDS ring (512 rows
// x 16 B). No __syncthreads / s_barrier anywhere: ring reuse is safe by per-wave
// program order alone (compute(m) precedes the gll overwriting chunk m by 2 bands).
// Taps read as contiguous 1 KB ds_read_b128 (64 lanes x consecutive 16B slots):
// zero bank conflicts by construction, no swizzle.
// Per-wave exact vmem ledger: body(t) issues {gll(t+6), store(t), diag(t+2)x9} = 11
// vmem ops; s_waitcnt vmcnt(12) retires chunk t+4 + dk(t) in worst-case order.
// Scattered 16B/lane staging & stores (stride 16 KB): the block's 8 col-waves are
// co-resident on one CU and touch the same 128 B lines within a band window -> L2
// merges; transaction arithmetic ~73K trans/CU ~= 7.6us, hidden.
// Geometry: 512 thr (8 waves) x 64 KB LDS -> 2 blocks/CU; grid (128,4) = 1 dose.

#define DIA_N   8192
#define DIA_M   4096
#define M4      (DIA_M / 4)   // 1024 f4 per row
#define BR      64            // rows per band
#define HALO    128           // max |offset|
#define RING    512           // private ring rows per wave (16 B each = 8 KB)
#define NB      32            // bands per wave
#define GROUP   (BR * NB)     // 2048 rows per block/wave
#define THREADS 512
#define NWAVES  (THREADS / 64)

typedef float f4 __attribute__((ext_vector_type(4)));
typedef __attribute__((address_space(3))) unsigned int       lds_uint;
typedef const __attribute__((address_space(1))) unsigned int glb_uint;

__global__ __launch_bounds__(THREADS, 4) void sparse_dia_kernel(
    const float* __restrict__ diags,   // [9, N]
    const float* __restrict__ other,   // [N, M]
    float* __restrict__ out)           // [N, M]
{
    constexpr int OFF[9] = {-128, -64, -8, -1, 0, 1, 8, 64, 128};

    __shared__ f4 ring[NWAVES][RING];  // 64 KB; ring[w] is wave w's PRIVATE ring

    const int tid  = threadIdx.x;
    const int wave = tid >> 6;
    const int lane = tid & 63;

    const int gr0  = blockIdx.y * GROUP;            // first output row
    const int col4 = blockIdx.x * NWAVES + wave;    // this wave's f4 column

    const f4* __restrict__ o4   = (const f4*)other;
    f4* __restrict__       out4 = (f4*)out;

    // ---- stage chunk m: logical rows [64m, 64m+64), abs row = gr0-HALO+64m+lane.
    // One gll instr: per-lane global addr (stride 16 KB), wave-uniform LDS base,
    // HW writes lane l at base + 16*l -> contiguous 1 KB in the private ring.
    auto gll64 = [&](int m) {
        int q = gr0 - HALO + m * BR + lane;
        q = (q < 0) ? 0 : (q >= DIA_N ? DIA_N - 1 : q);   // clamp; diag mask kills garbage
        const float* src = (const float*)&o4[(size_t)q * M4 + col4];
        __builtin_amdgcn_global_load_lds((glb_uint*)src,
            (lds_uint*)&ring[wave][(m * BR) & (RING - 1)], 16, 0, 0);
    };

    // ---- 9 diag loads -> registers; both paths issue EXACTLY 9 vmem ops (ledger).
    // Branch is (block,band)-uniform. Edge path: clamp addr, mask value to 0.
    auto load_diag = [&](int t, float (&dk)[9]) {
        const int r  = gr0 + t * BR + lane;
        const int lo = gr0 + t * BR - HALO;
        const int hi = gr0 + t * BR + (BR - 1) + HALO;
        if (lo >= 0 && hi < DIA_N) {
#pragma unroll
            for (int k = 0; k < 9; ++k)
                dk[k] = diags[k * DIA_N + r + OFF[k]];
        } else {
#pragma unroll
            for (int k = 0; k < 9; ++k) {
                const int q  = r + OFF[k];
                const int qc = (q < 0) ? 0 : (q >= DIA_N ? DIA_N - 1 : q);
                const float v = diags[k * DIA_N + qc];
                dk[k] = ((unsigned)q < (unsigned)DIA_N) ? v : 0.f;
            }
        }
    };

    // ---- compute band t from the private ring; 9 contiguous ds_read_b128 + store
    auto compute_store = [&](int t, const float (&dk)[9]) {
        const int L0 = t * BR + HALO + lane;   // logical row of this lane's output
        f4 a = (f4){0.f, 0.f, 0.f, 0.f};
#pragma unroll
        for (int k = 0; k < 9; ++k)
            a += dk[k] * ring[wave][(L0 + OFF[k]) & (RING - 1)];
        out4[(size_t)(gr0 + t * BR + lane) * M4 + col4] = a;
    };

    float dkA[9], dkB[9];

    // ---- prologue: chunks 0..5 (band-0 window + 1 ahead) + dk(0), dk(1); drain ----
#pragma unroll
    for (int m = 0; m < 6; ++m) gll64(m);
    load_diag(0, dkA);
    load_diag(1, dkB);
    asm volatile("s_waitcnt vmcnt(0)" ::: "memory");
    __builtin_amdgcn_sched_barrier(0);

    // ---- main loop: no barriers; per-wave counted vmcnt only.
    // Ring safety: chunk t+6 lands in slots [64t+384,448) mod 512, disjoint from
    // band t's live window [64t, 64t+320) mod 512; slot reuse (chunk m+8 over
    // chunk m) trails compute(m) by 2 bands in program order.
    auto body = [&](int t, float (&dk)[9]) {
        gll64(t + 6);
        asm volatile("s_waitcnt vmcnt(12)" ::: "memory");  // chunk t+4 & dk(t) retired;
        __builtin_amdgcn_sched_barrier(0);                 // ~12 ops stay in flight
        compute_store(t, dk);                              // reads dk BEFORE reload
        load_diag(t + 2, dk);                              // same-parity overwrite
    };

    for (int t = 0; t < NB - 2; t += 2) {   // static parity for dkA/dkB (rule #20)
        body(t,     dkA);
        body(t + 1, dkB);
    }

    // ---- tail: bands 30, 31 (chunks 0..35 all issued; just drain & compute) ----
    asm volatile("s_waitcnt vmcnt(0)" ::: "memory");
    __builtin_amdgcn_sched_barrier(0);
    compute_store(NB - 2, dkA);
    compute_store(NB - 1, dkB);
}

extern "C" void kernel_launch(void* const* d_in, const int* in_sizes, int n_in,
                              void* d_out, int out_size, void* d_ws, size_t ws_size,
                              hipStream_t stream) {
    const float* diags = (const float*)d_in[0];   // 9 * 8192 fp32
    const float* other = (const float*)d_in[1];   // 8192 * 4096 fp32
    float* out         = (float*)d_out;           // 8192 * 4096 fp32

    // 512 blocks = 2/CU (64 KB LDS each), 8 waves/block -> 16 waves/CU, one dose.
    dim3 block(THREADS, 1, 1);
    dim3 grid(M4 / NWAVES, DIA_N / GROUP, 1);     // (128, 4)
    sparse_dia_kernel<<<grid, block, 0, stream>>>(diags, other, out);
}

// Round 8
// 250.243 us; speedup vs baseline: 1.3824x; 1.3824x over previous
//
#include <hip/hip_runtime.h>

// SparseDIA (9 static offsets) @ dense: out[r,c] = sum_k diags[k, r+off_k] * other[r+off_k, c]
// N=8192, M=4096, fp32.
//
// R0-R7 synthesis: every structure costs ~(gathered bytes)/~15 TB/s; all prior
// rounds gather 9x16B per 16B output. Round-8 cuts the gather: lane = row
// (wave = 64 consecutive rows x 1 f4-col), so taps {0,+-64,+-128} live in a
// sliding REGISTER window w0..w4 (one new ds_read_b128 per output replaces 5).
// Taps {+-1,+-8} read from LDS (4 b128). Outputs bounce through an 8 KB LDS
// transpose (obuf) for coalesced stores (R7 lesson: never stride-16KB vmem).
// Net: 7 b128/output vs 9 b128 + 9 b32; diags -> registers (R6-proven).
// Swizzle col ^ ((row>>2)&7): 2-way (free) for all four access patterns.
// Skeleton = R5: gll staging, __syncthreads/band, 2 blocks/CU (64+16=80 KB LDS),
// clamp+zero-diag edge handling.

#define DIA_N   8192
#define DIA_M   4096
#define M4      (DIA_M / 4)   // 1024 f4 per row
#define CB      8             // f4 cols per block (128 B stripe)
#define BR      64            // rows per band (= 1 row per lane)
#define HALO    128           // max |offset|
#define RINGR   512           // ring rows = 8 chunks of 64 (power of 2)
#define NB      32            // bands per block
#define GROUP   (BR * NB)     // 2048 rows per block
#define THREADS 512           // 8 waves; wave = one f4-col x 64 rows

typedef float f4 __attribute__((ext_vector_type(4)));
typedef __attribute__((address_space(3))) unsigned int       lds_uint;
typedef const __attribute__((address_space(1))) unsigned int glb_uint;

__global__ __launch_bounds__(THREADS, 4) void sparse_dia_kernel(
    const float* __restrict__ diags,   // [9, N]
    const float* __restrict__ other,   // [N, M]
    float* __restrict__ out)           // [N, M]
{
    constexpr int OFF[9] = {-128, -64, -8, -1, 0, 1, 8, 64, 128};

    __shared__ f4 ring[RINGR][CB];     // 64 KB input window
    __shared__ f4 obuf[2][BR][CB];     // 16 KB output transpose, double-buffered

    const int tid  = threadIdx.x;
    const int wave = tid >> 6;         // = this wave's f4-col within the stripe
    const int lane = tid & 63;         // = row within band

    const int gr0 = blockIdx.y * GROUP;
    const int cb4 = blockIdx.x * CB;

    // staging lane roles: 8 rows x 8 cols per 1 KB gll instr
    const int lrow = lane >> 3;
    const int lcol = lane & 7;
    // ring[L][p] must hold global col p ^ ((L>>2)&7). For an instr at base
    // L = 64m + 8*wave: (L+lrow)>>2 & 7 = (2*wave + (lrow>>2)) & 7 -- chunk-invariant.
    const int scol = lcol ^ ((2 * wave + (lrow >> 2)) & 7);

    const f4* __restrict__ o4   = (const f4*)other;
    f4* __restrict__       out4 = (f4*)out;

    // ---- stage chunk m (logical rows [64m, 64m+64)); 1 gll instr per wave ----
    auto stage_chunk = [&](int m) {
        const int L = 64 * m + 8 * wave;
        int q = gr0 - HALO + L + lrow;
        q = (q < 0) ? 0 : (q >= DIA_N ? DIA_N - 1 : q);   // clamp; diag mask kills garbage
        const float* src = (const float*)&o4[(size_t)q * M4 + cb4 + scol];
        __builtin_amdgcn_global_load_lds((glb_uint*)src,
            (lds_uint*)&ring[L & (RINGR - 1)][0], 16, 0, 0);
    };

    // ---- swizzled ring read for this wave's col at logical row L ----
    auto rd = [&](int L) -> f4 {
        const int s = L & (RINGR - 1);
        return ring[s][wave ^ ((s >> 2) & 7)];
    };

    // ---- 9 diag loads -> registers (coalesced 256 B per instr; 8x wave-redundant, cached) ----
    auto ldiag = [&](int t, float (&dk)[9]) {
        const int r  = gr0 + t * BR + lane;
        const int lo = gr0 + t * BR - HALO;
        const int hi = gr0 + t * BR + (BR - 1) + HALO;
        if (lo >= 0 && hi < DIA_N) {                       // block+band-uniform branch
#pragma unroll
            for (int k = 0; k < 9; ++k)
                dk[k] = diags[k * DIA_N + r + OFF[k]];
        } else {
#pragma unroll
            for (int k = 0; k < 9; ++k) {
                const int q  = r + OFF[k];
                const int qc = (q < 0) ? 0 : (q >= DIA_N ? DIA_N - 1 : q);
                const float v = diags[k * DIA_N + qc];
                dk[k] = ((unsigned)q < (unsigned)DIA_N) ? v : 0.f;
            }
        }
    };

    f4 w0, w1, w2, w3, w4;             // sliding window: taps -128,-64,0,+64,+128
    float dkA[9], dkB[9];

    // ---- prologue: chunks 0..4 = band-0 window; diags(0); init w1..w4 ----
#pragma unroll
    for (int m = 0; m < 5; ++m) stage_chunk(m);
    ldiag(0, dkA);
    __syncthreads();
    w1 = rd(lane);                     // chunk 0 (becomes w0 = tap -128 at t=0)
    w2 = rd(64 + lane);                // chunk 1
    w3 = rd(128 + lane);               // chunk 2
    w4 = rd(192 + lane);               // chunk 3

    // ---- per band: {stage t+5, diag t+1, slide window + 4 near reads, fma,
    //      obuf write, barrier, coalesced store of band t} ----
    auto body = [&](int t, float (&cur)[9], float (&nxt)[9]) {
        stage_chunk(t + 5);            // overwrites chunk t-3: not in live window t..t+4
        ldiag(t + 1, nxt);             // t+1==NB reads clamped+masked rows: safe, unused

        const int L0 = HALO + t * BR + lane;   // this lane's output row (logical)
        w0 = w1; w1 = w2; w2 = w3; w3 = w4;
        w4 = rd(L0 + 128);             // chunk t+4 (landed via barrier t-1)
        const f4 vm8 = rd(L0 - 8), vm1 = rd(L0 - 1);
        const f4 vp1 = rd(L0 + 1), vp8 = rd(L0 + 8);

        f4 a = cur[0] * w0;
        a += cur[1] * w1;  a += cur[2] * vm8; a += cur[3] * vm1;
        a += cur[4] * w2;  a += cur[5] * vp1; a += cur[6] * vp8;
        a += cur[7] * w3;  a += cur[8] * w4;

        obuf[t & 1][lane][wave ^ ((lane >> 2) & 7)] = a;   // 2-way swizzled write
        __syncthreads();               // drains gll(t+5) + joins obuf transpose

        // store band t coalesced: wave covers 8 rows x full 128 B stripe
        const int row = 8 * wave + (lane >> 3);
        const int cp  = (lane & 7) ^ ((row >> 2) & 7);
        out4[(size_t)(gr0 + t * BR + row) * M4 + cb4 + (lane & 7)] =
            obuf[t & 1][row][cp];
        // obuf[t&1] next written at t+2, after barrier(t+1): no race
    };

    for (int t = 0; t < NB; t += 2) {  // static dk parity (rule #20)
        body(t,     dkA, dkB);
        body(t + 1, dkB, dkA);
    }
}

extern "C" void kernel_launch(void* const* d_in, const int* in_sizes, int n_in,
                              void* d_out, int out_size, void* d_ws, size_t ws_size,
                              hipStream_t stream) {
    const float* diags = (const float*)d_in[0];   // 9 * 8192 fp32
    const float* other = (const float*)d_in[1];   // 8192 * 4096 fp32
    float* out         = (float*)d_out;           // 8192 * 4096 fp32

    // 512 blocks = 2/CU (80 KB LDS each), 8 waves/block -> 16 waves/CU.
    dim3 block(THREADS, 1, 1);
    dim3 grid(M4 / CB, DIA_N / GROUP, 1);         // (128, 4)
    sparse_dia_kernel<<<grid, block, 0, stream>>>(diags, other, out);
}

// Round 9
// 246.568 us; speedup vs baseline: 1.4030x; 1.0149x over previous
//
#include <hip/hip_runtime.h>

// SparseDIA (9 static offsets) @ dense: out[r,c] = sum_k diags[k, r+off_k] * other[r+off_k, c]
// N=8192, M=4096, fp32.
//
// R4-R8 synthesis: every pipe <40% busy; the pin is the per-band gll CONVOY --
// each barrier waits on the last global_load_lds of the previous chunk, and all
// prior structures gave a chunk only ~1 iteration of slack before its use.
// Round-9: depth-3 prefetch. Ring = 8 chunks x 128 rows x 128 B = 128 KB (whole
// CU LDS, 1 block/CU, 1024 thr). Window = chunks t..t+2; gll(t+5) issued at
// iter t -> ~3 iterations (>9K cycles) of latency tolerance per chunk.
// Diags in REGISTERS with a 4-deep static rotation (d0..d3), loaded 3 iters
// ahead -> zero LDS diag traffic, and the per-wave vmem FIFO is exact:
//   iter t: [gll(t+5)=1, diag(t+3)=9 | vmcnt(33) | s_barrier | compute, store=1]
// vmcnt(33) retires exactly iter t-3's batch (= chunk t+2 and dk(t)), leaving
// chunks t+3,t+4,t+5 in flight across the barrier (T3/T4, never drain to 0).
// Bank swizzle: R5's proven col ^ (s&7) (2 lanes per phys col within each
// 16-lane b128 phase -> near-free); R8's (s>>2) variant measured 4-way worse.
// Edges: clamp addresses, zero the diag -> products vanish (R5/R6-proven).

#define DIA_N   8192
#define DIA_M   4096
#define M4      (DIA_M / 4)   // 1024 f4 per row
#define CB      8             // f4 cols per block (128 B stripe)
#define BR      128           // rows per band = rows per chunk
#define HALO    128           // max |offset|
#define RINGR   1024          // ring rows = 8 chunks (power of 2) = 128 KB
#define NB      32            // bands per block
#define GROUP   (BR * NB)     // 4096 rows per block
#define THREADS 1024          // 16 waves

typedef float f4 __attribute__((ext_vector_type(4)));
typedef __attribute__((address_space(3))) unsigned int       lds_uint;
typedef const __attribute__((address_space(1))) unsigned int glb_uint;

__global__ __launch_bounds__(THREADS) void sparse_dia_kernel(
    const float* __restrict__ diags,   // [9, N]
    const float* __restrict__ other,   // [N, M]
    float* __restrict__ out)           // [N, M]
{
    constexpr int OFF[9] = {-128, -64, -8, -1, 0, 1, 8, 64, 128};

    __shared__ f4 ring[RINGR][CB];     // 128 KB; rows linear (gll dest), cols swizzled

    const int tid  = threadIdx.x;
    const int gr0  = blockIdx.y * GROUP;
    const int cb4  = blockIdx.x * CB;

    const int wave = tid >> 6;
    const int lane = tid & 63;
    const int lrow = lane >> 3;        // row within this wave's 8-row gll instr
    const int lcol = lane & 7;         // LDS phys col this lane fills
    const int scol = lcol ^ lrow;      // pre-swizzled GLOBAL source col (s&7 == lrow)

    const int c = tid & 7;             // output f4 col
    const int i = tid >> 3;            // band row 0..127 (1 output/thread/band)

    const f4* __restrict__ o4   = (const f4*)other;
    f4* __restrict__       out4 = (f4*)out;

    // ---- stage chunk m (logical rows [BR*m, BR*m+BR)); 1 gll instr per wave ----
    auto stage_chunk = [&](int m) {
        const int L = BR * m + 8 * wave;               // this wave's 8-row base
        int q = gr0 - HALO + L + lrow;
        q = (q < 0) ? 0 : (q >= DIA_N ? DIA_N - 1 : q);  // clamp; diag mask kills garbage
        const float* src = (const float*)&o4[(size_t)q * M4 + cb4 + scol];
        __builtin_amdgcn_global_load_lds((glb_uint*)src,
            (lds_uint*)&ring[L & (RINGR - 1)][0], 16, 0, 0);
    };

    // ---- 9 diag loads -> registers; both paths issue EXACTLY 9 vmem ops (ledger).
    auto load_diag = [&](int t, float (&dk)[9]) {
        const int r  = gr0 + t * BR + i;
        const int lo = gr0 + t * BR - HALO;
        const int hi = gr0 + t * BR + (BR - 1) + HALO;
        if (lo >= 0 && hi < DIA_N) {                   // (block,band)-uniform branch
#pragma unroll
            for (int k = 0; k < 9; ++k)
                dk[k] = diags[k * DIA_N + r + OFF[k]];
        } else {
#pragma unroll
            for (int k = 0; k < 9; ++k) {
                const int q  = r + OFF[k];
                const int qc = (q < 0) ? 0 : (q >= DIA_N ? DIA_N - 1 : q);
                const float v = diags[k * DIA_N + qc];
                dk[k] = ((unsigned)q < (unsigned)DIA_N) ? v : 0.f;
            }
        }
    };

    // ---- compute band t from ring (9 swizzled ds_read_b128) + register diags ----
    auto compute_store = [&](int t, const float (&dk)[9]) {
        const int L0 = HALO + t * BR + i;              // this thread's logical row
        f4 a = (f4){0.f, 0.f, 0.f, 0.f};
#pragma unroll
        for (int k = 0; k < 9; ++k) {
            const int s = (L0 + OFF[k]) & (RINGR - 1);
            a += dk[k] * ring[s][c ^ (s & 7)];
        }
        out4[(size_t)(gr0 + t * BR + i) * M4 + cb4 + c] = a;   // 1 vmem (counted)
    };

    // ---- per-iter body. FIFO at the wait (steady state, t>=3):
    //   [batch t-3: gll(t+2), diag(t)x9] st(t-3) [batch t-2]x10 st(t-2)
    //   [batch t-1]x10 st(t-1) [batch t]x10  -> ops after batch t-3's diag = 33.
    // vmcnt(33) == "iter t-3 fully retired": chunk t+2 landed, dk(t) loaded.
    // gll(t+5) overwrites chunk t-3's slot: last read by compute(t-3), two
    // barriers ago for every wave -> no race.
    auto body = [&](int t, const float (&use)[9], float (&ld)[9]) {
        stage_chunk(t + 5);                            // dummy past NB: clamped, safe slot
        load_diag(t + 3, ld);                          // dummy past NB: masked/unused
        asm volatile("s_waitcnt vmcnt(33)" ::: "memory");
        __builtin_amdgcn_sched_barrier(0);
        __builtin_amdgcn_s_barrier();                  // all waves' chunk t+2 visible
        __builtin_amdgcn_sched_barrier(0);
        compute_store(t, use);
    };

    float d0[9], d1[9], d2[9], d3[9];

    // ---- prologue: chunks 0..4 (window 0..2 + 2 ahead) + dk(0..2); full drain ----
#pragma unroll
    for (int m = 0; m < 5; ++m) stage_chunk(m);
    load_diag(0, d0);
    load_diag(1, d1);
    load_diag(2, d2);
    asm volatile("s_waitcnt vmcnt(0)" ::: "memory");
    __builtin_amdgcn_s_barrier();
    __builtin_amdgcn_sched_barrier(0);

    // ---- main loop: static 4-phase rotation (rule #20: no runtime reg indexing) ----
    for (int t = 0; t < NB; t += 4) {
        body(t,     d0, d3);    // uses dk(t),   loads dk(t+3) -> d3
        body(t + 1, d1, d0);
        body(t + 2, d2, d1);
        body(t + 3, d3, d2);
    }
}

extern "C" void kernel_launch(void* const* d_in, const int* in_sizes, int n_in,
                              void* d_out, int out_size, void* d_ws, size_t ws_size,
                              hipStream_t stream) {
    const float* diags = (const float*)d_in[0];   // 9 * 8192 fp32
    const float* other = (const float*)d_in[1];   // 8192 * 4096 fp32
    float* out         = (float*)d_out;           // 8192 * 4096 fp32

    // 256 blocks = exactly 1/CU (128 KB LDS), 16 waves each.
    dim3 block(THREADS, 1, 1);
    dim3 grid(M4 / CB, DIA_N / GROUP, 1);         // (128, 2)
    sparse_dia_kernel<<<grid, block, 0, stream>>>(diags, other, out);
}